// Round 7
// baseline (273.360 us; speedup 1.0000x reference)
//
#include <hip/hip_runtime.h>
#include <cstdint>
#include <cstddef>

typedef unsigned short u16t;
typedef __attribute__((ext_vector_type(4))) float f32x4;
typedef __attribute__((ext_vector_type(4))) int i32x4;
typedef __attribute__((ext_vector_type(4))) unsigned int u32x4;
typedef __attribute__((ext_vector_type(8))) __bf16 bf16x8;
typedef __attribute__((ext_vector_type(4))) __bf16 bf16x4;
typedef __attribute__((ext_vector_type(8))) unsigned short u16x8;
typedef __attribute__((ext_vector_type(4))) unsigned short u16x4;

#define INFF __builtin_inff()

__device__ __forceinline__ u16t f2b(float f) {
  union { float f; unsigned u; } x; x.f = f;
  unsigned r = x.u + 0x7FFFu + ((x.u >> 16) & 1u);   // RNE
  return (u16t)(r >> 16);
}

// async global->LDS, 16B per lane. LDS dest = wave-uniform base + lane*16.
__device__ __forceinline__ void gload16(const u16t* g, u16t* l) {
  __builtin_amdgcn_global_load_lds((const __attribute__((address_space(1))) void*)g,
                                   (__attribute__((address_space(3))) void*)l, 16, 0, 0);
}

// ---------------- fused prep: cvt x, cvt ctx, packed cmask bits ----------------
// blocks [0,2048): x cvt; [2048,10240): ctx cvt; 10240: cmask bit-pack.
__global__ __launch_bounds__(256) void k_prep(const float* __restrict__ x,
                                              const float* __restrict__ ctx,
                                              u16t* __restrict__ x16,
                                              u16t* __restrict__ ctx16,
                                              const int* __restrict__ cmask,
                                              unsigned int* __restrict__ cmbits) {
  const int bx = blockIdx.x, tid = threadIdx.x;
  if (bx < 2048) {
    int i = bx * 256 + tid;
    f32x4 v = *(const f32x4*)(x + (size_t)i * 4);
    u16x4 o;
    o[0] = f2b(v[0]); o[1] = f2b(v[1]); o[2] = f2b(v[2]); o[3] = f2b(v[3]);
    *(u16x4*)(x16 + (size_t)i * 4) = o;
  } else if (bx < 10240) {
    int i = (bx - 2048) * 256 + tid;
    f32x4 v = *(const f32x4*)(ctx + (size_t)i * 4);
    u16x4 o;
    o[0] = f2b(v[0]); o[1] = f2b(v[1]); o[2] = f2b(v[2]); o[3] = f2b(v[3]);
    *(u16x4*)(ctx16 + (size_t)i * 4) = o;
  } else {
    // 256 threads: thread t packs word (b = t>>7, w = t&127) of cmask bits
    int b = tid >> 7, wdi = tid & 127;
    const int* cp = cmask + b * 4096 + wdi * 32;
    unsigned int bits = 0;
#pragma unroll
    for (int i = 0; i < 32; ++i) bits |= (cp[i] != 0 ? 1u : 0u) << i;
    cmbits[tid] = bits;
  }
}

// ---------------- fused 3x weight transpose: fp32 (1024 x C) -> bf16 (C x 1024) ----------------
__global__ __launch_bounds__(256) void k_transpose_w3(const float* __restrict__ Wq,
                                                      const float* __restrict__ Wkv,
                                                      const float* __restrict__ Wout,
                                                      u16t* __restrict__ WqT,
                                                      u16t* __restrict__ WkvT,
                                                      u16t* __restrict__ WoutT) {
  __shared__ float tile[64 * 65];
  const int t = threadIdx.x;
  const int bxx = blockIdx.x;
  const float* src; u16t* dst; int C, cb;
  if (bxx < 16)      { src = Wq;   dst = WqT;   C = 1024; cb = bxx * 64; }
  else if (bxx < 48) { src = Wkv;  dst = WkvT;  C = 2048; cb = (bxx - 16) * 64; }
  else               { src = Wout; dst = WoutT; C = 1024; cb = (bxx - 48) * 64; }
  const int rb = blockIdx.y * 64;
#pragma unroll
  for (int it = 0; it < 4; ++it) {
    int c = it * 256 + t;
    int r = c >> 4, ch = c & 15;
    f32x4 v = *(const f32x4*)(src + (size_t)(rb + r) * C + cb + ch * 4);
    float* dp = &tile[r * 65 + ch * 4];
    dp[0] = v[0]; dp[1] = v[1]; dp[2] = v[2]; dp[3] = v[3];
  }
  __syncthreads();
#pragma unroll
  for (int it = 0; it < 2; ++it) {
    int c = it * 256 + t;
    int dr = c >> 3, ch = c & 7;
    u16x8 o;
#pragma unroll
    for (int i = 0; i < 8; ++i) o[i] = f2b(tile[(ch * 8 + i) * 65 + dr]);
    *(u16x8*)(dst + (size_t)(cb + dr) * 1024 + rb + ch * 8) = o;
  }
}

// ---------------- bf16 GEMM: C(MxN) = oscale * A(MxK) @ Bt(NxK)^T ----------------
// MODE 0: bf16 C.  MODE 1: f32 C + bias.  MODE 2: kv-dual (k->C, v->C2=vT transposed).
template <int MODE>
__global__ __launch_bounds__(256) void k_gemm_bt(const u16t* __restrict__ A,
                                                 const u16t* __restrict__ Bt,
                                                 void* __restrict__ C,
                                                 u16t* __restrict__ C2,
                                                 const float* __restrict__ bias,
                                                 float oscale,
                                                 int K, int lda, int ldb, int ldc, int nbx) {
  __shared__ u16t As[128 * 64];
  __shared__ u16t Bs[128 * 64];
  const int tid = threadIdx.x;
  const int lane = tid & 63, wid = tid >> 6;
  const int l16 = lane & 15, lg = lane >> 4;
  const int wr = wid >> 1, wc = wid & 1;
  const int g = blockIdx.x, per = gridDim.x >> 3;
  const int w = (g & 7) * per + (g >> 3);
  const int bx = w % nbx, by = w / nbx;
  const int brow = by * 128, bcol = bx * 128;
  const int sr = lane >> 3, chs = lane & 7;
  f32x4 acc[4][4] = {};

  for (int k0 = 0; k0 < K; k0 += 64) {
#pragma unroll
    for (int it = 0; it < 4; ++it) {
      int row = it * 32 + wid * 8 + sr;
      int ch = chs ^ (row & 7);
      gload16(A + (size_t)(brow + row) * lda + k0 + ch * 8, &As[it * 2048 + wid * 512]);
      gload16(Bt + (size_t)(bcol + row) * ldb + k0 + ch * 8, &Bs[it * 2048 + wid * 512]);
    }
    __syncthreads();
#pragma unroll
    for (int kk = 0; kk < 2; ++kk) {
      bf16x8 af[4], bfv[4];
#pragma unroll
      for (int mi = 0; mi < 4; ++mi) {
        int row = wr * 64 + mi * 16 + l16;
        int kch = (kk * 4 + lg) ^ (row & 7);
        af[mi] = *(const bf16x8*)(&As[row * 64 + kch * 8]);
      }
#pragma unroll
      for (int ni = 0; ni < 4; ++ni) {
        int row = wc * 64 + ni * 16 + l16;
        int kch = (kk * 4 + lg) ^ (row & 7);
        bfv[ni] = *(const bf16x8*)(&Bs[row * 64 + kch * 8]);
      }
#pragma unroll
      for (int mi = 0; mi < 4; ++mi)
#pragma unroll
        for (int ni = 0; ni < 4; ++ni)
          acc[mi][ni] = __builtin_amdgcn_mfma_f32_16x16x32_bf16(af[mi], bfv[ni], acc[mi][ni], 0, 0, 0);
    }
    __syncthreads();
  }

  if (MODE == 2 && bcol >= 1024) {
#pragma unroll
    for (int mi = 0; mi < 4; ++mi) {
#pragma unroll
      for (int ni = 0; ni < 4; ++ni) {
        int vcol = bcol - 1024 + wc * 64 + ni * 16 + l16;
        int h = vcol >> 6, hd = vcol & 63;
        int row0 = brow + wr * 64 + mi * 16 + lg * 4;
        int bb = row0 >> 12, pos = row0 & 4095;
        u16x4 o4;
#pragma unroll
        for (int j = 0; j < 4; ++j) o4[j] = f2b(acc[mi][ni][j]);
        *(u16x4*)(C2 + ((size_t)((bb * 16 + h) * 64 + hd)) * 4096 + pos) = o4;
      }
    }
    return;
  }
#pragma unroll
  for (int mi = 0; mi < 4; ++mi) {
#pragma unroll
    for (int ni = 0; ni < 4; ++ni) {
#pragma unroll
      for (int j = 0; j < 4; ++j) {
        size_t row = (size_t)brow + wr * 64 + mi * 16 + lg * 4 + j;
        int col = bcol + wc * 64 + ni * 16 + l16;
        float v = acc[mi][ni][j] * oscale;
        if (MODE == 1) {
          v += bias[col];
          __builtin_nontemporal_store(v, (float*)C + row * ldc + col);
        } else {
          ((u16t*)C)[row * ldc + col] = f2b(v);
        }
      }
    }
  }
}

// ---------------- fused attention: 32 q-rows/wave, no mid-tile global loads ----------------
// Swapped QK^T (S^T = K @ Q^T): lane holds S[q=l16][kv=kb*16+lg*4+j], two q-halves.
// cmask from packed bits (reg-dbuf'd one tile ahead); ds is scalar per tile.
// Barrier uses vmcnt(16): the 16 NT pre-stores stay in flight across the barrier.
__global__ __launch_bounds__(256) void k_attn(const u16t* __restrict__ k16,
                                              const u16t* __restrict__ vT16,
                                              const u16t* __restrict__ q16,
                                              const unsigned int* __restrict__ cmbits,
                                              const float* __restrict__ dsim,
                                              const float* __restrict__ beta_p,
                                              const int* __restrict__ mask,
                                              float* __restrict__ pre,
                                              u16t* __restrict__ O16) {
  __shared__ u16t Ks[2][128 * 64];   // [kv 128][hd 64] swizzled   32 KB
  __shared__ u16t Vs[2][64 * 128];   // [hd 64][kv 128] swizzled   32 KB
  __shared__ u16t Ps[4 * 16 * 128];  // per-wave P tile (per half) 16 KB

  const int tid = threadIdx.x;
  const int lane = tid & 63, wid = tid >> 6;
  const int l16 = lane & 15, lg = lane >> 4;
  // XCD swizzle (256 = 8 x 32): each (b,h)'s 8 n-blocks stay on one XCD
  const int g = blockIdx.x;
  const int w = (g & 7) * 32 + (g >> 3);
  const int nb = w & 7, hb = w >> 3;
  const int h = hb & 15, b = hb >> 4;
  const int qrow0 = nb * 128 + wid * 32;

  bf16x8 aqA0, aqA1, aqB0, aqB1;
  {
    const u16t* qp = q16 + (size_t)(b * 1024 + qrow0 + l16) * 1024 + h * 64 + lg * 8;
    aqA0 = *(const bf16x8*)(qp);
    aqA1 = *(const bf16x8*)(qp + 32);
    aqB0 = *(const bf16x8*)(qp + 16 * 1024);
    aqB1 = *(const bf16x8*)(qp + 16 * 1024 + 32);
  }
  const bool qmA = mask[b * 1024 + qrow0 + l16] != 0;
  const bool qmB = mask[b * 1024 + qrow0 + 16 + l16] != 0;

  const float beta = beta_p[0];
  const float ds40 = dsim[b * 4 + 0] * beta, ds41 = dsim[b * 4 + 1] * beta;
  const float ds42 = dsim[b * 4 + 2] * beta, ds43 = dsim[b * 4 + 3] * beta;

  float mrowA = -INFF, lsumA = 0.f, mrowB = -INFF, lsumB = 0.f;
  f32x4 oA[4] = {}, oB[4] = {};

  const u16t* kbase = k16 + (size_t)b * 4096 * 1024 + (size_t)h * 64;
  const u16t* vbase = vT16 + (size_t)(b * 16 + h) * 64 * 4096;
  float* prerowA = pre + (size_t)((b * 16 + h) * 1024 + qrow0 + l16) * 4096;
  float* prerowB = prerowA + (size_t)16 * 4096;
  const u32x4* cmw = (const u32x4*)(cmbits + b * 128);
  u16t* Pw = &Ps[wid * 2048];
  char* Pwb = (char*)Pw + l16 * 256;
  const int pswz = (l16 & 7) << 4;

  auto stage = [&](int bufi, int kv0s) {
    u16t* Kb = &Ks[bufi][wid * 2048];
    u16t* Vb = &Vs[bufi][wid * 2048];
#pragma unroll
    for (int it = 0; it < 4; ++it) {
      int row = wid * 32 + it * 8 + (lane >> 3);
      int ch = (lane & 7) ^ (row & 7);
      gload16(kbase + (size_t)(kv0s + row) * 1024 + ch * 8, Kb + it * 512);
    }
#pragma unroll
    for (int it = 0; it < 4; ++it) {
      int row = wid * 16 + it * 4 + (lane >> 4);
      int ch = (lane & 15) ^ (row & 7);
      gload16(vbase + (size_t)row * 4096 + kv0s + ch * 8, Vb + it * 512);
    }
  };

  u32x4 Wc = cmw[0];
  int cur = 0;
  stage(0, 0);
  __syncthreads();

  for (int t = 0; t < 32; ++t) {
    u32x4 Wn = Wc;
    if (t + 1 < 32) {
      Wn = cmw[t + 1];                 // issued BEFORE stage: consuming Wc never drains stores
      stage(cur ^ 1, (t + 1) * 128);   // prefetch overlaps compute
    }
    asm volatile("" ::: "memory");
    const u16t* Kc = &Ks[cur][0];
    const u16t* Vc = &Vs[cur][0];
    const int kv0 = t * 128;
    const int d = t >> 3;              // doc index: tiles never cross doc boundary
    const float ds_t = (d & 1) ? ((d & 2) ? ds43 : ds41) : ((d & 2) ? ds42 : ds40);

    // S^T = K @ Q^T for both q-halves, sharing bk fragments
    f32x4 sA[8], sB[8];
    __builtin_amdgcn_s_setprio(1);
#pragma unroll
    for (int kb = 0; kb < 8; ++kb) {
      int row = kb * 16 + l16;
      bf16x8 bk0 = *(const bf16x8*)(&Kc[row * 64 + ((lg ^ (row & 7)) << 3)]);
      bf16x8 bk1 = *(const bf16x8*)(&Kc[row * 64 + (((4 + lg) ^ (row & 7)) << 3)]);
      f32x4 a0 = {0.f, 0.f, 0.f, 0.f};
      a0 = __builtin_amdgcn_mfma_f32_16x16x32_bf16(bk0, aqA0, a0, 0, 0, 0);
      a0 = __builtin_amdgcn_mfma_f32_16x16x32_bf16(bk1, aqA1, a0, 0, 0, 0);
      sA[kb] = a0;
      f32x4 b0 = {0.f, 0.f, 0.f, 0.f};
      b0 = __builtin_amdgcn_mfma_f32_16x16x32_bf16(bk0, aqB0, b0, 0, 0, 0);
      b0 = __builtin_amdgcn_mfma_f32_16x16x32_bf16(bk1, aqB1, b0, 0, 0, 0);
      sB[kb] = b0;
    }
    __builtin_amdgcn_s_setprio(0);

    // ---------- half A: pre-store, bias(bits)+mask, online softmax, Ps, pa->regs ----------
    float tmax = -INFF;
#pragma unroll
    for (int kb = 0; kb < 8; ++kb) {
      const int cb2 = kv0 + kb * 16 + lg * 4;
      __builtin_nontemporal_store(sA[kb], (f32x4*)(prerowA + cb2));
      const unsigned int sh = Wc[kb >> 1] >> ((kb & 1) * 16 + lg * 4);
#pragma unroll
      for (int j = 0; j < 4; ++j) {
        float bias = ((sh >> j) & 1u) ? ds_t : -INFF;
        float t2 = sA[kb][j] + bias;
        if (!qmA) t2 = 0.f;
        if (t2 == 0.f) t2 = -INFF;
        sA[kb][j] = t2;
        tmax = fmaxf(tmax, t2);
      }
    }
    tmax = fmaxf(tmax, __shfl_xor(tmax, 16, 64));
    tmax = fmaxf(tmax, __shfl_xor(tmax, 32, 64));
    const float moldA = mrowA;
    const float mnA = fmaxf(moldA, tmax);
    mrowA = mnA;
    float psum = 0.f;
#pragma unroll
    for (int kb = 0; kb < 8; ++kb) {
      bf16x4 pb;
#pragma unroll
      for (int j = 0; j < 4; ++j) {
        float p = (mnA == -INFF) ? 0.f : __expf(sA[kb][j] - mnA);
        psum += p;
        pb[j] = (__bf16)p;
      }
      *(bf16x4*)(Pwb + ((kb * 32 + lg * 8) ^ pswz)) = pb;
    }
    asm volatile("" ::: "memory");
    psum += __shfl_xor(psum, 16, 64);
    psum += __shfl_xor(psum, 32, 64);
    if (__all(mnA == moldA)) {
      lsumA += psum;
    } else {
      const float fs = (mnA == -INFF) ? 0.f : __expf(moldA - mnA);
      lsumA = lsumA * fs + psum;
      float f0 = __shfl(fs, lg * 4 + 0, 64), f1 = __shfl(fs, lg * 4 + 1, 64);
      float f2 = __shfl(fs, lg * 4 + 2, 64), f3 = __shfl(fs, lg * 4 + 3, 64);
#pragma unroll
      for (int ni = 0; ni < 4; ++ni) {
        oA[ni][0] *= f0; oA[ni][1] *= f1; oA[ni][2] *= f2; oA[ni][3] *= f3;
      }
    }
    bf16x8 paA0 = *(const bf16x8*)(Pwb + ((0 * 64 + lg * 16) ^ pswz));
    bf16x8 paA1 = *(const bf16x8*)(Pwb + ((1 * 64 + lg * 16) ^ pswz));
    bf16x8 paA2 = *(const bf16x8*)(Pwb + ((2 * 64 + lg * 16) ^ pswz));
    bf16x8 paA3 = *(const bf16x8*)(Pwb + ((3 * 64 + lg * 16) ^ pswz));
    asm volatile("" ::: "memory");

    // ---------- half B ----------
    tmax = -INFF;
#pragma unroll
    for (int kb = 0; kb < 8; ++kb) {
      const int cb2 = kv0 + kb * 16 + lg * 4;
      __builtin_nontemporal_store(sB[kb], (f32x4*)(prerowB + cb2));
      const unsigned int sh = Wc[kb >> 1] >> ((kb & 1) * 16 + lg * 4);
#pragma unroll
      for (int j = 0; j < 4; ++j) {
        float bias = ((sh >> j) & 1u) ? ds_t : -INFF;
        float t2 = sB[kb][j] + bias;
        if (!qmB) t2 = 0.f;
        if (t2 == 0.f) t2 = -INFF;
        sB[kb][j] = t2;
        tmax = fmaxf(tmax, t2);
      }
    }
    tmax = fmaxf(tmax, __shfl_xor(tmax, 16, 64));
    tmax = fmaxf(tmax, __shfl_xor(tmax, 32, 64));
    const float moldB = mrowB;
    const float mnB = fmaxf(moldB, tmax);
    mrowB = mnB;
    psum = 0.f;
#pragma unroll
    for (int kb = 0; kb < 8; ++kb) {
      bf16x4 pb;
#pragma unroll
      for (int j = 0; j < 4; ++j) {
        float p = (mnB == -INFF) ? 0.f : __expf(sB[kb][j] - mnB);
        psum += p;
        pb[j] = (__bf16)p;
      }
      *(bf16x4*)(Pwb + ((kb * 32 + lg * 8) ^ pswz)) = pb;
    }
    asm volatile("" ::: "memory");
    psum += __shfl_xor(psum, 16, 64);
    psum += __shfl_xor(psum, 32, 64);
    if (__all(mnB == moldB)) {
      lsumB += psum;
    } else {
      const float fs = (mnB == -INFF) ? 0.f : __expf(moldB - mnB);
      lsumB = lsumB * fs + psum;
      float f0 = __shfl(fs, lg * 4 + 0, 64), f1 = __shfl(fs, lg * 4 + 1, 64);
      float f2 = __shfl(fs, lg * 4 + 2, 64), f3 = __shfl(fs, lg * 4 + 3, 64);
#pragma unroll
      for (int ni = 0; ni < 4; ++ni) {
        oB[ni][0] *= f0; oB[ni][1] *= f1; oB[ni][2] *= f2; oB[ni][3] *= f3;
      }
    }
    bf16x8 paB0 = *(const bf16x8*)(Pwb + ((0 * 64 + lg * 16) ^ pswz));
    bf16x8 paB1 = *(const bf16x8*)(Pwb + ((1 * 64 + lg * 16) ^ pswz));
    bf16x8 paB2 = *(const bf16x8*)(Pwb + ((2 * 64 + lg * 16) ^ pswz));
    bf16x8 paB3 = *(const bf16x8*)(Pwb + ((3 * 64 + lg * 16) ^ pswz));

    // ---------- PV for both halves, sharing vb fragments ----------
    __builtin_amdgcn_s_setprio(1);
#pragma unroll
    for (int kk2 = 0; kk2 < 4; ++kk2) {
      bf16x8 pa_a = (kk2 == 0) ? paA0 : (kk2 == 1) ? paA1 : (kk2 == 2) ? paA2 : paA3;
      bf16x8 pa_b = (kk2 == 0) ? paB0 : (kk2 == 1) ? paB1 : (kk2 == 2) ? paB2 : paB3;
#pragma unroll
      for (int ni = 0; ni < 4; ++ni) {
        int vrow = ni * 16 + l16;
        bf16x8 vb = *(const bf16x8*)(&Vc[vrow * 128 + (((kk2 * 4 + lg) ^ (vrow & 7)) << 3)]);
        oA[ni] = __builtin_amdgcn_mfma_f32_16x16x32_bf16(pa_a, vb, oA[ni], 0, 0, 0);
        oB[ni] = __builtin_amdgcn_mfma_f32_16x16x32_bf16(pa_b, vb, oB[ni], 0, 0, 0);
      }
    }
    __builtin_amdgcn_s_setprio(0);

    // counted-vmcnt barrier: drain Wn + stage (9 oldest), keep 16 NT stores in flight
    asm volatile("s_waitcnt vmcnt(16) lgkmcnt(0)" ::: "memory");
    __builtin_amdgcn_sched_barrier(0);
    __builtin_amdgcn_s_barrier();
    __builtin_amdgcn_sched_barrier(0);
    Wc = Wn;
    cur ^= 1;
  }

  float lsA0 = __shfl(lsumA, lg * 4 + 0, 64), lsA1 = __shfl(lsumA, lg * 4 + 1, 64);
  float lsA2 = __shfl(lsumA, lg * 4 + 2, 64), lsA3 = __shfl(lsumA, lg * 4 + 3, 64);
  float lsB0 = __shfl(lsumB, lg * 4 + 0, 64), lsB1 = __shfl(lsumB, lg * 4 + 1, 64);
  float lsB2 = __shfl(lsumB, lg * 4 + 2, 64), lsB3 = __shfl(lsumB, lg * 4 + 3, 64);
#pragma unroll
  for (int ni = 0; ni < 4; ++ni) {
    size_t rowA = (size_t)b * 1024 + qrow0 + lg * 4;
    int col = h * 64 + ni * 16 + l16;
    O16[(rowA + 0) * 1024 + col] = f2b(oA[ni][0] / lsA0);
    O16[(rowA + 1) * 1024 + col] = f2b(oA[ni][1] / lsA1);
    O16[(rowA + 2) * 1024 + col] = f2b(oA[ni][2] / lsA2);
    O16[(rowA + 3) * 1024 + col] = f2b(oA[ni][3] / lsA3);
    size_t rowB = rowA + 16;
    O16[(rowB + 0) * 1024 + col] = f2b(oB[ni][0] / lsB0);
    O16[(rowB + 1) * 1024 + col] = f2b(oB[ni][1] / lsB1);
    O16[(rowB + 2) * 1024 + col] = f2b(oB[ni][2] / lsB2);
    O16[(rowB + 3) * 1024 + col] = f2b(oB[ni][3] / lsB3);
  }
}

extern "C" void kernel_launch(void* const* d_in, const int* in_sizes, int n_in,
                              void* d_out, int out_size, void* d_ws, size_t ws_size,
                              hipStream_t stream) {
  const float* x = (const float*)d_in[0];
  const float* ctx = (const float*)d_in[1];
  const float* dsim = (const float*)d_in[2];
  const int* mask = (const int*)d_in[3];
  const int* cmask = (const int*)d_in[4];
  const float* Wq = (const float*)d_in[5];
  const float* Wkv = (const float*)d_in[6];
  const float* Wout = (const float*)d_in[7];
  const float* bout = (const float*)d_in[8];
  const float* beta = (const float*)d_in[9];

  char* ws = (char*)d_ws;
  u16t* q16 = (u16t*)(ws + (0ull << 20));     //  4 MiB (2048x1024), pre-scaled by d^-0.5
  u16t* k16 = (u16t*)(ws + (4ull << 20));     // 16 MiB (8192x1024) k half, compact
  u16t* vT16 = (u16t*)(ws + (36ull << 20));   // 16 MiB (2,16,64,4096)
  u16t* O16 = (u16t*)(ws + (52ull << 20));    //  4 MiB (2048x1024)
  u16t* x16 = (u16t*)(ws + (56ull << 20));    //  4 MiB
  u16t* ctx16 = (u16t*)(ws + (60ull << 20));  // 16 MiB
  u16t* WqT = (u16t*)(ws + (76ull << 20));    //  2 MiB
  u16t* WkvT = (u16t*)(ws + (78ull << 20));   //  4 MiB
  u16t* WoutT = (u16t*)(ws + (82ull << 20));  //  2 MiB
  unsigned int* cmbits = (unsigned int*)(ws + (84ull << 20)); // 1 KiB (2 x 128 u32)

  float* outp = (float*)d_out;
  float* pre = outp + (size_t)2 * 1024 * 1024;

  // fused cvt(x), cvt(ctx), cmask bit-pack
  k_prep<<<10241, 256, 0, stream>>>(x, ctx, x16, ctx16, cmask, cmbits);
  // fused 3x weight transpose
  k_transpose_w3<<<dim3(64, 16), 256, 0, stream>>>(Wq, Wkv, Wout, WqT, WkvT, WoutT);

  // q = (x @ Wq) * d^-0.5   (2048x1024) bf16  (scale fold is exact: 2^-5)
  k_gemm_bt<0><<<128, 256, 0, stream>>>(x16, WqT, (void*)q16, nullptr, nullptr, 0.03125f, 1024, 1024, 1024, 1024, 8);
  // kv GEMM: k half -> k16 (compact), v half -> vT16 (transposed per head)
  k_gemm_bt<2><<<1024, 256, 0, stream>>>(ctx16, WkvT, (void*)k16, vT16, nullptr, 1.0f, 1024, 1024, 1024, 1024, 16);
  // fused QK^T + pre-store + softmax + PV  (256 blocks x 4 waves x 32 q-rows)
  k_attn<<<256, 256, 0, stream>>>(k16, vT16, q16, cmbits, dsim, beta, mask, pre, O16);
  // out = O @ Wout + bout  (f32)
  k_gemm_bt<1><<<128, 256, 0, stream>>>(O16, WoutT, d_out, nullptr, bout, 1.0f, 1024, 1024, 1024, 1024, 8);
}

// Round 8
// 263.354 us; speedup vs baseline: 1.0380x; 1.0380x over previous
//
#include <hip/hip_runtime.h>
#include <cstdint>
#include <cstddef>

typedef unsigned short u16t;
typedef __attribute__((ext_vector_type(4))) float f32x4;
typedef __attribute__((ext_vector_type(4))) int i32x4;
typedef __attribute__((ext_vector_type(4))) unsigned int u32x4;
typedef __attribute__((ext_vector_type(8))) __bf16 bf16x8;
typedef __attribute__((ext_vector_type(4))) __bf16 bf16x4;
typedef __attribute__((ext_vector_type(8))) unsigned short u16x8;
typedef __attribute__((ext_vector_type(4))) unsigned short u16x4;

#define INFF __builtin_inff()

__device__ __forceinline__ u16t f2b(float f) {
  union { float f; unsigned u; } x; x.f = f;
  unsigned r = x.u + 0x7FFFu + ((x.u >> 16) & 1u);   // RNE
  return (u16t)(r >> 16);
}

// async global->LDS, 16B per lane. LDS dest = wave-uniform base + lane*16.
__device__ __forceinline__ void gload16(const u16t* g, u16t* l) {
  __builtin_amdgcn_global_load_lds((const __attribute__((address_space(1))) void*)g,
                                   (__attribute__((address_space(3))) void*)l, 16, 0, 0);
}

// ---------------- fused prep: cvt x, cvt ctx, packed cmask bits ----------------
// blocks [0,2048): x cvt; [2048,10240): ctx cvt; 10240: cmask bit-pack.
__global__ __launch_bounds__(256) void k_prep(const float* __restrict__ x,
                                              const float* __restrict__ ctx,
                                              u16t* __restrict__ x16,
                                              u16t* __restrict__ ctx16,
                                              const int* __restrict__ cmask,
                                              unsigned int* __restrict__ cmbits) {
  const int bx = blockIdx.x, tid = threadIdx.x;
  if (bx < 2048) {
    int i = bx * 256 + tid;
    f32x4 v = *(const f32x4*)(x + (size_t)i * 4);
    u16x4 o;
    o[0] = f2b(v[0]); o[1] = f2b(v[1]); o[2] = f2b(v[2]); o[3] = f2b(v[3]);
    *(u16x4*)(x16 + (size_t)i * 4) = o;
  } else if (bx < 10240) {
    int i = (bx - 2048) * 256 + tid;
    f32x4 v = *(const f32x4*)(ctx + (size_t)i * 4);
    u16x4 o;
    o[0] = f2b(v[0]); o[1] = f2b(v[1]); o[2] = f2b(v[2]); o[3] = f2b(v[3]);
    *(u16x4*)(ctx16 + (size_t)i * 4) = o;
  } else {
    // 256 threads: thread t packs word (b = t>>7, w = t&127) of cmask bits
    int b = tid >> 7, wdi = tid & 127;
    const int* cp = cmask + b * 4096 + wdi * 32;
    unsigned int bits = 0;
#pragma unroll
    for (int i = 0; i < 32; ++i) bits |= (cp[i] != 0 ? 1u : 0u) << i;
    cmbits[tid] = bits;
  }
}

// ---------------- fused 3x weight transpose: fp32 (1024 x C) -> bf16 (C x 1024) ----------------
__global__ __launch_bounds__(256) void k_transpose_w3(const float* __restrict__ Wq,
                                                      const float* __restrict__ Wkv,
                                                      const float* __restrict__ Wout,
                                                      u16t* __restrict__ WqT,
                                                      u16t* __restrict__ WkvT,
                                                      u16t* __restrict__ WoutT) {
  __shared__ float tile[64 * 65];
  const int t = threadIdx.x;
  const int bxx = blockIdx.x;
  const float* src; u16t* dst; int C, cb;
  if (bxx < 16)      { src = Wq;   dst = WqT;   C = 1024; cb = bxx * 64; }
  else if (bxx < 48) { src = Wkv;  dst = WkvT;  C = 2048; cb = (bxx - 16) * 64; }
  else               { src = Wout; dst = WoutT; C = 1024; cb = (bxx - 48) * 64; }
  const int rb = blockIdx.y * 64;
#pragma unroll
  for (int it = 0; it < 4; ++it) {
    int c = it * 256 + t;
    int r = c >> 4, ch = c & 15;
    f32x4 v = *(const f32x4*)(src + (size_t)(rb + r) * C + cb + ch * 4);
    float* dp = &tile[r * 65 + ch * 4];
    dp[0] = v[0]; dp[1] = v[1]; dp[2] = v[2]; dp[3] = v[3];
  }
  __syncthreads();
#pragma unroll
  for (int it = 0; it < 2; ++it) {
    int c = it * 256 + t;
    int dr = c >> 3, ch = c & 7;
    u16x8 o;
#pragma unroll
    for (int i = 0; i < 8; ++i) o[i] = f2b(tile[(ch * 8 + i) * 65 + dr]);
    *(u16x8*)(dst + (size_t)(cb + dr) * 1024 + rb + ch * 8) = o;
  }
}

// ---------------- bf16 GEMM: C(MxN) = oscale * A(MxK) @ Bt(NxK)^T ----------------
// MODE 0: bf16 C.  MODE 1: f32 C + bias.  MODE 2: kv-dual (k->C, v->C2=vT transposed).
template <int MODE>
__global__ __launch_bounds__(256) void k_gemm_bt(const u16t* __restrict__ A,
                                                 const u16t* __restrict__ Bt,
                                                 void* __restrict__ C,
                                                 u16t* __restrict__ C2,
                                                 const float* __restrict__ bias,
                                                 float oscale,
                                                 int K, int lda, int ldb, int ldc, int nbx) {
  __shared__ u16t As[128 * 64];
  __shared__ u16t Bs[128 * 64];
  const int tid = threadIdx.x;
  const int lane = tid & 63, wid = tid >> 6;
  const int l16 = lane & 15, lg = lane >> 4;
  const int wr = wid >> 1, wc = wid & 1;
  const int g = blockIdx.x, per = gridDim.x >> 3;
  const int w = (g & 7) * per + (g >> 3);
  const int bx = w % nbx, by = w / nbx;
  const int brow = by * 128, bcol = bx * 128;
  const int sr = lane >> 3, chs = lane & 7;
  f32x4 acc[4][4] = {};

  for (int k0 = 0; k0 < K; k0 += 64) {
#pragma unroll
    for (int it = 0; it < 4; ++it) {
      int row = it * 32 + wid * 8 + sr;
      int ch = chs ^ (row & 7);
      gload16(A + (size_t)(brow + row) * lda + k0 + ch * 8, &As[it * 2048 + wid * 512]);
      gload16(Bt + (size_t)(bcol + row) * ldb + k0 + ch * 8, &Bs[it * 2048 + wid * 512]);
    }
    __syncthreads();
#pragma unroll
    for (int kk = 0; kk < 2; ++kk) {
      bf16x8 af[4], bfv[4];
#pragma unroll
      for (int mi = 0; mi < 4; ++mi) {
        int row = wr * 64 + mi * 16 + l16;
        int kch = (kk * 4 + lg) ^ (row & 7);
        af[mi] = *(const bf16x8*)(&As[row * 64 + kch * 8]);
      }
#pragma unroll
      for (int ni = 0; ni < 4; ++ni) {
        int row = wc * 64 + ni * 16 + l16;
        int kch = (kk * 4 + lg) ^ (row & 7);
        bfv[ni] = *(const bf16x8*)(&Bs[row * 64 + kch * 8]);
      }
#pragma unroll
      for (int mi = 0; mi < 4; ++mi)
#pragma unroll
        for (int ni = 0; ni < 4; ++ni)
          acc[mi][ni] = __builtin_amdgcn_mfma_f32_16x16x32_bf16(af[mi], bfv[ni], acc[mi][ni], 0, 0, 0);
    }
    __syncthreads();
  }

  if (MODE == 2 && bcol >= 1024) {
#pragma unroll
    for (int mi = 0; mi < 4; ++mi) {
#pragma unroll
      for (int ni = 0; ni < 4; ++ni) {
        int vcol = bcol - 1024 + wc * 64 + ni * 16 + l16;
        int h = vcol >> 6, hd = vcol & 63;
        int row0 = brow + wr * 64 + mi * 16 + lg * 4;
        int bb = row0 >> 12, pos = row0 & 4095;
        u16x4 o4;
#pragma unroll
        for (int j = 0; j < 4; ++j) o4[j] = f2b(acc[mi][ni][j]);
        *(u16x4*)(C2 + ((size_t)((bb * 16 + h) * 64 + hd)) * 4096 + pos) = o4;
      }
    }
    return;
  }
#pragma unroll
  for (int mi = 0; mi < 4; ++mi) {
#pragma unroll
    for (int ni = 0; ni < 4; ++ni) {
#pragma unroll
      for (int j = 0; j < 4; ++j) {
        size_t row = (size_t)brow + wr * 64 + mi * 16 + lg * 4 + j;
        int col = bcol + wc * 64 + ni * 16 + l16;
        float v = acc[mi][ni][j] * oscale;
        if (MODE == 1) {
          v += bias[col];
          __builtin_nontemporal_store(v, (float*)C + row * ldc + col);
        } else {
          ((u16t*)C)[row * ldc + col] = f2b(v);
        }
      }
    }
  }
}

// ---------------- fused attention (swapped-QK^T: S^T = K @ Q^T) ----------------
// R6 structure (16 q-rows/wave, 512 blocks = 2 blocks/CU) with ZERO mid-tile
// global vector loads: cmask from packed bits (register-dbuf'd, scalarized),
// ds scalar per tile. Per-tile vmem issue order = [8 gload_lds][8 NT stores];
// barrier vmcnt(8) drains exactly the stage loads, keeps all 8 pre-stores in flight.
__global__ __launch_bounds__(256) void k_attn(const u16t* __restrict__ k16,
                                              const u16t* __restrict__ vT16,
                                              const u16t* __restrict__ q16,
                                              const unsigned int* __restrict__ cmbits,
                                              const float* __restrict__ dsim,
                                              const float* __restrict__ beta_p,
                                              const int* __restrict__ mask,
                                              float* __restrict__ pre,
                                              u16t* __restrict__ O16) {
  __shared__ u16t Ks[2][128 * 64];   // [kv 128][hd 64] swizzled
  __shared__ u16t Vs[2][64 * 128];   // [hd 64][kv 128] swizzled
  __shared__ u16t Ps[4 * 16 * 128];  // per-wave P tile [q 16][kv 128] swizzled

  const int tid = threadIdx.x;
  const int lane = tid & 63, wid = tid >> 6;
  const int l16 = lane & 15, lg = lane >> 4;
  // XCD swizzle: w = (g%8)*64 + g/8 ; nb fastest so same (b,h) groups stay on one XCD
  const int g = blockIdx.x;
  const int w = (g & 7) * 64 + (g >> 3);
  const int nb = w & 15, hb = w >> 4;
  const int h = hb & 15, b = hb >> 4;
  const int qrow0 = nb * 64 + wid * 16;

  bf16x8 aq0, aq1;
  {
    const u16t* qp = q16 + (size_t)(b * 1024 + qrow0 + l16) * 1024 + h * 64 + lg * 8;
    aq0 = *(const bf16x8*)(qp);
    aq1 = *(const bf16x8*)(qp + 32);
  }
  const bool qm = mask[b * 1024 + qrow0 + l16] != 0;

  const float beta = beta_p[0];
  const float ds40 = dsim[b * 4 + 0] * beta, ds41 = dsim[b * 4 + 1] * beta;
  const float ds42 = dsim[b * 4 + 2] * beta, ds43 = dsim[b * 4 + 3] * beta;

  float mrow = -INFF, lsum = 0.f;
  f32x4 o[4] = {};

  const u16t* kbase = k16 + (size_t)b * 4096 * 1024 + (size_t)h * 64;
  const u16t* vbase = vT16 + (size_t)(b * 16 + h) * 64 * 4096;
  float* prerow = pre + (size_t)((b * 16 + h) * 1024 + qrow0 + l16) * 4096;  // this lane's q row
  const u32x4* cmw = (const u32x4*)(cmbits + b * 128);   // wave-uniform -> s_load
  u16t* Pw = &Ps[wid * 2048];
  char* Pwb = (char*)Pw + l16 * 256;      // this lane's P row base (bytes)
  const int pswz = (l16 & 7) << 4;        // row-XOR swizzle

  auto stage = [&](int bufi, int kv0s) {
    u16t* Kb = &Ks[bufi][wid * 2048];
    u16t* Vb = &Vs[bufi][wid * 2048];
#pragma unroll
    for (int it = 0; it < 4; ++it) {
      int row = wid * 32 + it * 8 + (lane >> 3);
      int ch = (lane & 7) ^ (row & 7);
      gload16(kbase + (size_t)(kv0s + row) * 1024 + ch * 8, Kb + it * 512);
    }
#pragma unroll
    for (int it = 0; it < 4; ++it) {
      int row = wid * 16 + it * 4 + (lane >> 4);
      int ch = (lane & 15) ^ (row & 7);
      gload16(vbase + (size_t)row * 4096 + kv0s + ch * 8, Vb + it * 512);
    }
  };

  u32x4 Wc = cmw[0];
  int cur = 0;
  stage(0, 0);
  __syncthreads();

  for (int t = 0; t < 32; ++t) {
    u32x4 Wn = Wc;
    if (t + 1 < 32) {
      Wn = cmw[t + 1];                 // scalar load (lgkm) -- never touches vmcnt
      stage(cur ^ 1, (t + 1) * 128);   // prefetch overlaps compute
    }
    asm volatile("" ::: "memory");     // pin stage loads before the NT stores
    const u16t* Kc = &Ks[cur][0];
    const u16t* Vc = &Vs[cur][0];
    const int kv0 = t * 128;
    const int d = t >> 3;              // doc index: tiles never cross doc boundary
    const float ds_t = (d & 1) ? ((d & 2) ? ds43 : ds41) : ((d & 2) ? ds42 : ds40);

    // S^T = K @ Q^T : lane gets S[q=l16][kv=kb*16+lg*4+j] (already d^-0.5 scaled)
    f32x4 s[8];
#pragma unroll
    for (int kb = 0; kb < 8; ++kb) {
      f32x4 acc = {0.f, 0.f, 0.f, 0.f};
      int row = kb * 16 + l16;
      bf16x8 bk0 = *(const bf16x8*)(&Kc[row * 64 + ((lg ^ (row & 7)) << 3)]);
      bf16x8 bk1 = *(const bf16x8*)(&Kc[row * 64 + (((4 + lg) ^ (row & 7)) << 3)]);
      acc = __builtin_amdgcn_mfma_f32_16x16x32_bf16(bk0, aq0, acc, 0, 0, 0);
      acc = __builtin_amdgcn_mfma_f32_16x16x32_bf16(bk1, aq1, acc, 0, 0, 0);
      s[kb] = acc;
    }

    // vectorized pre-store (NT), bias from mask bits (registers only), row-max
    float tmax = -INFF;
#pragma unroll
    for (int kb = 0; kb < 8; ++kb) {
      const int colb = kv0 + kb * 16 + lg * 4;   // 4 | 1024 => same doc for j=0..3
      __builtin_nontemporal_store(s[kb], (f32x4*)(prerow + colb));
      const unsigned int sh = Wc[kb >> 1] >> ((kb & 1) * 16 + lg * 4);
#pragma unroll
      for (int j = 0; j < 4; ++j) {
        float bias = ((sh >> j) & 1u) ? ds_t : -INFF;
        float t2 = s[kb][j] + bias;    // masked col: -inf
        if (!qm) t2 = 0.f;
        if (t2 == 0.f) t2 = -INFF;     // faithful zero->-inf
        s[kb][j] = t2;
        tmax = fmaxf(tmax, t2);
      }
    }
    tmax = fmaxf(tmax, __shfl_xor(tmax, 16, 64));
    tmax = fmaxf(tmax, __shfl_xor(tmax, 32, 64));
    const float mold = mrow;
    const float mn = fmaxf(mold, tmax);
    const bool nochange = __all(mn == mold);
    mrow = mn;

    // P = exp(t - m) -> 8B LDS writes in A-frag layout [q=l16][kv]
    float psum = 0.f;
#pragma unroll
    for (int kb = 0; kb < 8; ++kb) {
      bf16x4 pb;
#pragma unroll
      for (int j = 0; j < 4; ++j) {
        float p = (mn == -INFF) ? 0.f : __expf(s[kb][j] - mn);
        psum += p;
        pb[j] = (__bf16)p;
      }
      *(bf16x4*)(Pwb + ((kb * 32 + lg * 8) ^ pswz)) = pb;
    }
    asm volatile("" ::: "memory");
    psum += __shfl_xor(psum, 16, 64);
    psum += __shfl_xor(psum, 32, 64);

    if (nochange) {
      lsum += psum;                      // fs == 1 for every lane: skip rescale
    } else {
      const float fs = (mn == -INFF) ? 0.f : __expf(mold - mn);
      lsum = lsum * fs + psum;
      float fsj[4];
#pragma unroll
      for (int j = 0; j < 4; ++j) fsj[j] = __shfl(fs, lg * 4 + j, 64);
#pragma unroll
      for (int ni = 0; ni < 4; ++ni)
#pragma unroll
        for (int j = 0; j < 4; ++j) o[ni][j] *= fsj[j];
    }

    // O += P @ V
#pragma unroll
    for (int kk2 = 0; kk2 < 4; ++kk2) {
      bf16x8 pa = *(const bf16x8*)(Pwb + ((kk2 * 64 + lg * 16) ^ pswz));
#pragma unroll
      for (int ni = 0; ni < 4; ++ni) {
        int vrow = ni * 16 + l16;
        bf16x8 vb = *(const bf16x8*)(&Vc[vrow * 128 + (((kk2 * 4 + lg) ^ (vrow & 7)) << 3)]);
        o[ni] = __builtin_amdgcn_mfma_f32_16x16x32_bf16(pa, vb, o[ni], 0, 0, 0);
      }
    }

    // counted-vmcnt barrier: outstanding vmem = 8 stage + 8 NT stores.
    // vmcnt(8) drains exactly the stage loads; the stores stay in flight.
    asm volatile("s_waitcnt vmcnt(8) lgkmcnt(0)" ::: "memory");
    __builtin_amdgcn_sched_barrier(0);
    __builtin_amdgcn_s_barrier();
    __builtin_amdgcn_sched_barrier(0);
    Wc = Wn;
    cur ^= 1;
  }

  float lsj[4];
#pragma unroll
  for (int j = 0; j < 4; ++j) lsj[j] = __shfl(lsum, lg * 4 + j, 64);
#pragma unroll
  for (int ni = 0; ni < 4; ++ni) {
#pragma unroll
    for (int j = 0; j < 4; ++j) {
      size_t row = (size_t)b * 1024 + qrow0 + lg * 4 + j;
      int col = h * 64 + ni * 16 + l16;
      O16[row * 1024 + col] = f2b(o[ni][j] / lsj[j]);
    }
  }
}

extern "C" void kernel_launch(void* const* d_in, const int* in_sizes, int n_in,
                              void* d_out, int out_size, void* d_ws, size_t ws_size,
                              hipStream_t stream) {
  const float* x = (const float*)d_in[0];
  const float* ctx = (const float*)d_in[1];
  const float* dsim = (const float*)d_in[2];
  const int* mask = (const int*)d_in[3];
  const int* cmask = (const int*)d_in[4];
  const float* Wq = (const float*)d_in[5];
  const float* Wkv = (const float*)d_in[6];
  const float* Wout = (const float*)d_in[7];
  const float* bout = (const float*)d_in[8];
  const float* beta = (const float*)d_in[9];

  char* ws = (char*)d_ws;
  u16t* q16 = (u16t*)(ws + (0ull << 20));     //  4 MiB (2048x1024), pre-scaled by d^-0.5
  u16t* k16 = (u16t*)(ws + (4ull << 20));     // 16 MiB (8192x1024) k half, compact
  u16t* vT16 = (u16t*)(ws + (36ull << 20));   // 16 MiB (2,16,64,4096)
  u16t* O16 = (u16t*)(ws + (52ull << 20));    //  4 MiB (2048x1024)
  u16t* x16 = (u16t*)(ws + (56ull << 20));    //  4 MiB
  u16t* ctx16 = (u16t*)(ws + (60ull << 20));  // 16 MiB
  u16t* WqT = (u16t*)(ws + (76ull << 20));    //  2 MiB
  u16t* WkvT = (u16t*)(ws + (78ull << 20));   //  4 MiB
  u16t* WoutT = (u16t*)(ws + (82ull << 20));  //  2 MiB
  unsigned int* cmbits = (unsigned int*)(ws + (84ull << 20)); // 1 KiB (2 x 128 u32)

  float* outp = (float*)d_out;
  float* pre = outp + (size_t)2 * 1024 * 1024;

  // fused cvt(x), cvt(ctx), cmask bit-pack
  k_prep<<<10241, 256, 0, stream>>>(x, ctx, x16, ctx16, cmask, cmbits);
  // fused 3x weight transpose
  k_transpose_w3<<<dim3(64, 16), 256, 0, stream>>>(Wq, Wkv, Wout, WqT, WkvT, WoutT);

  // q = (x @ Wq) * d^-0.5   (2048x1024) bf16  (scale fold is exact: 2^-5)
  k_gemm_bt<0><<<128, 256, 0, stream>>>(x16, WqT, (void*)q16, nullptr, nullptr, 0.03125f, 1024, 1024, 1024, 1024, 8);
  // kv GEMM: k half -> k16 (compact), v half -> vT16 (transposed per head)
  k_gemm_bt<2><<<1024, 256, 0, stream>>>(ctx16, WkvT, (void*)k16, vT16, nullptr, 1.0f, 1024, 1024, 1024, 1024, 16);
  // fused QK^T + pre-store + softmax + PV  (512 blocks x 4 waves x 16 q-rows)
  k_attn<<<512, 256, 0, stream>>>(k16, vT16, q16, cmbits, dsim, beta, mask, pre, O16);
  // out = O @ Wout + bout  (f32)
  k_gemm_bt<1><<<128, 256, 0, stream>>>(O16, WoutT, d_out, nullptr, bout, 1.0f, 1024, 1024, 1024, 1024, 8);
}